// Round 4
// baseline (209.045 us; speedup 1.0000x reference)
//
#include <hip/hip_runtime.h>

// InterestTransformerDecoder: B=512, L=L1=256, D=128.
// Inputs are FLOAT32 (per the reference's explicit jnp.float32): d_in[0]=seq i32,
// [1]=last i32, [2]=seq1 i32, [3]=hist_1 f32[512*256*128], [4]=hist_2 f32,
// [5]=W f32[128*128]. Output f32[512*128].
// R1 failed: 149.5KB dynamic LDS launch reject. R2/R3 failed: inputs were read
// as bf16 while they are f32 -> NaNs -> relu(NaN)=0 -> all-zero output.
// R4: f32 I/O; convert to bf16 in-register only for the two MFMA GEMMs
// (S = H1.H1^T and h_self = w.H1); everything else f32.
// One block per batch, 512 threads (8 waves). Static LDS 61,704 B.

using u16 = unsigned short;
using u32 = unsigned int;
typedef __attribute__((ext_vector_type(8))) short bf16x8;
typedef __attribute__((ext_vector_type(4))) float f32x4;
typedef __attribute__((ext_vector_type(4))) u32 u32x4;
typedef __attribute__((ext_vector_type(2))) u32 u32x2;

#define KST 136   // Kbuf row stride (u16): 128 data + 8 pad
#define TST 40    // Tbuf row stride (u16): 32 data + 8 pad
#define WSTR 40   // WST row stride (u16)

__device__ __forceinline__ u16 f2bf(float f) {
  union { float f; u32 i; } v; v.f = f;
  u32 r = v.i + 0x7FFFu + ((v.i >> 16) & 1u);   // RNE
  return (u16)(r >> 16);
}
__device__ __forceinline__ bf16x8 as_bf(u32x4 x) {
  union { u32x4 u; bf16x8 b; } c; c.u = x; return c.b;
}
// pack 8 consecutive f32 -> 8 bf16 (u32x4), accumulate sum of squares (f32)
__device__ __forceinline__ u32x4 pack_bf8(const float* p, float& ss) {
  const float4 a = *(const float4*)p;
  const float4 c = *(const float4*)(p + 4);
  ss += a.x*a.x + a.y*a.y + a.z*a.z + a.w*a.w
      + c.x*c.x + c.y*c.y + c.z*c.z + c.w*c.w;
  u32x4 v;
  v.x = (u32)f2bf(a.x) | ((u32)f2bf(a.y) << 16);
  v.y = (u32)f2bf(a.z) | ((u32)f2bf(a.w) << 16);
  v.z = (u32)f2bf(c.x) | ((u32)f2bf(c.y) << 16);
  v.w = (u32)f2bf(c.z) | ((u32)f2bf(c.w) << 16);
  return v;
}

// Stage one 32-row j-tile into Kbuf (row-major bf16), Tbuf (transposed bf16),
// and per-row inv-norm. v = 8 bf16 of row (wv*4+q), cols m16*8..+7; ss = that
// lane's f32 sum of squares over those 8 elements.
__device__ __forceinline__ void stage_tile(u32x4 v, float ss, u16* kb, u16* tb,
                                           float* invt, int wv, int q, int m16) {
  const int row = wv * 4 + q;            // tile-local row 0..31
  *(u32x4*)&kb[row * KST + m16 * 8] = v;
  ss += __shfl_xor(ss, 1); ss += __shfl_xor(ss, 2);
  ss += __shfl_xor(ss, 4); ss += __shfl_xor(ss, 8);
  if (m16 == 0) invt[row] = rsqrtf(ss + 0.01f);
  u32 w0 = v.x, w1 = v.y, w2 = v.z, w3 = v.w;
  // 4x4 u32 transpose across the 4 q-lanes (xor 16, then xor 32)
  {
    const int s1 = q & 1;
    u32 xa = s1 ? w0 : w1;
    u32 xb = s1 ? w2 : w3;
    xa = __shfl_xor(xa, 16);
    xb = __shfl_xor(xb, 16);
    if (s1) { w0 = xa; w2 = xb; } else { w1 = xa; w3 = xb; }
    const int s2 = q >> 1;
    u32 ya = s2 ? w0 : w2;
    u32 yb = s2 ? w1 : w3;
    ya = __shfl_xor(ya, 32);
    yb = __shfl_xor(yb, 32);
    if (s2) { w0 = ya; w1 = yb; } else { w2 = ya; w3 = yb; }
  }
  const int d0   = m16 * 8 + q * 2;      // d-row pair held by this lane
  const int base = wv * 4;               // tile-local j base (4 cols)
  u32x2 lo; lo.x = (w0 & 0xffffu) | (w1 << 16); lo.y = (w2 & 0xffffu) | (w3 << 16);
  u32x2 hi; hi.x = (w0 >> 16) | (w1 & 0xffff0000u); hi.y = (w2 >> 16) | (w3 & 0xffff0000u);
  *(u32x2*)&tb[d0 * TST + base]       = lo;
  *(u32x2*)&tb[(d0 + 1) * TST + base] = hi;
}

__launch_bounds__(512)
__global__ void itd_fused(const int* __restrict__ seq,
                          const int* __restrict__ lastseq,
                          const int* __restrict__ seq1,
                          const float* __restrict__ h1g,
                          const float* __restrict__ h2g,
                          const float* __restrict__ wg,
                          float* __restrict__ outg) {
  __shared__ u16 Kbuf[2][32 * KST];          // 17408 B
  __shared__ u16 Tbuf[2][128 * TST];         // 20480 B
  __shared__ u16 WST[8][2 * 16 * WSTR];      // 20480 B (per wave, per rt half)
  __shared__ float MK[256], LM[256], HLacc[128], HH[128], INVt[2][32], SC[2];

  const int b    = blockIdx.x;
  const int t    = threadIdx.x;
  const int lane = t & 63;
  const int wv   = t >> 6;
  const int q    = lane >> 4;
  const int m16  = lane & 15;

  const float* h1b = h1g + (size_t)b * 32768;

  if (t < 128) HLacc[t] = 0.f;
  if (t < 256) {
    float m = (seq[b * 256 + t] != 0) ? 1.f : 0.f;
    MK[t] = m;
    LM[t] = m * (float)lastseq[b * 256 + t];
  }

  // ---- Q fragments (both rt tiles) + inv-norms, from global f32 ----
  u32x4 av[2][4];
  float invi[2][4];
  #pragma unroll
  for (int rt = 0; rt < 2; ++rt) {
    const int i0 = wv * 32 + rt * 16;
    float ss = 0.f;
    #pragma unroll
    for (int s = 0; s < 4; ++s)
      av[rt][s] = pack_bf8(&h1b[(i0 + m16) * 128 + s * 32 + q * 8], ss);
    ss += __shfl_xor(ss, 16);
    ss += __shfl_xor(ss, 32);
    const float invrow = rsqrtf(ss + 0.01f);   // lane holds row i0+m16's inv
    #pragma unroll
    for (int r = 0; r < 4; ++r) invi[rt][r] = __shfl(invrow, q * 4 + r);
  }

  // staging element base for this thread within a 32-row tile:
  // row = t>>4 (tile-local), cols (t&15)*8
  const int srow = t >> 4;
  const int scol = (t & 15) * 8;
  {
    float ss = 0.f;
    u32x4 v0 = pack_bf8(&h1b[srow * 128 + scol], ss);
    stage_tile(v0, ss, Kbuf[0], Tbuf[0], INVt[0], wv, q, m16);
  }
  __syncthreads();

  // ---- streamed self cosine attention ----
  const f32x4 fz = {0.f, 0.f, 0.f, 0.f};
  f32x4 acc[2][8];
  #pragma unroll
  for (int rt = 0; rt < 2; ++rt)
    #pragma unroll
    for (int dt = 0; dt < 8; ++dt) acc[rt][dt] = fz;
  float wpart[2][4] = {{0.f,0.f,0.f,0.f},{0.f,0.f,0.f,0.f}};
  u16* wst0 = &WST[wv][0];
  u16* wst1 = &WST[wv][16 * WSTR];

  for (int jt = 0; jt < 8; ++jt) {
    const int cur = jt & 1;
    float4 pfa, pfb;
    if (jt < 7) {                             // prefetch next tile (8 f32)
      const float* np = &h1b[(jt + 1) * 4096 + srow * 128 + scol];
      pfa = *(const float4*)np;
      pfb = *(const float4*)(np + 4);
    }

    // S = Q . K^T for both rt tiles (B-fragments shared)
    f32x4 Sa[2] = {fz, fz}, Sb[2] = {fz, fz};
    const u16* kb = Kbuf[cur];
    #pragma unroll
    for (int s = 0; s < 4; ++s) {
      bf16x8 ba = *(const bf16x8*)&kb[m16 * KST + s * 32 + q * 8];
      bf16x8 bb = *(const bf16x8*)&kb[(16 + m16) * KST + s * 32 + q * 8];
      bf16x8 a0 = as_bf(av[0][s]);
      bf16x8 a1 = as_bf(av[1][s]);
      Sa[0] = __builtin_amdgcn_mfma_f32_16x16x32_bf16(a0, ba, Sa[0], 0, 0, 0);
      Sb[0] = __builtin_amdgcn_mfma_f32_16x16x32_bf16(a0, bb, Sb[0], 0, 0, 0);
      Sa[1] = __builtin_amdgcn_mfma_f32_16x16x32_bf16(a1, ba, Sa[1], 0, 0, 0);
      Sb[1] = __builtin_amdgcn_mfma_f32_16x16x32_bf16(a1, bb, Sb[1], 0, 0, 0);
    }
    const float invja = INVt[cur][m16];
    const float invjb = INVt[cur][16 + m16];
    const float mja = MK[jt * 32 + m16];
    const float mjb = MK[jt * 32 + 16 + m16];
    #pragma unroll
    for (int rt = 0; rt < 2; ++rt) {
      u16* wr = rt ? wst1 : wst0;
      #pragma unroll
      for (int r = 0; r < 4; ++r) {
        const float wa = __expf(Sa[rt][r] * (invi[rt][r] * invja)) * mja;
        const float wb = __expf(Sb[rt][r] * (invi[rt][r] * invjb)) * mjb;
        wpart[rt][r] += wa + wb;
        wr[(q * 4 + r) * WSTR + m16]      = f2bf(wa);   // C-layout -> A-layout
        wr[(q * 4 + r) * WSTR + 16 + m16] = f2bf(wb);
      }
    }
    __threadfence_block();
    const bf16x8 aw0 = *(const bf16x8*)&wst0[m16 * WSTR + q * 8];
    const bf16x8 aw1 = *(const bf16x8*)&wst1[m16 * WSTR + q * 8];
    const u16* tb = Tbuf[cur];
    #pragma unroll
    for (int dt = 0; dt < 8; ++dt) {
      const bf16x8 bt = *(const bf16x8*)&tb[(dt * 16 + m16) * TST + q * 8];
      acc[0][dt] = __builtin_amdgcn_mfma_f32_16x16x32_bf16(aw0, bt, acc[0][dt], 0, 0, 0);
      acc[1][dt] = __builtin_amdgcn_mfma_f32_16x16x32_bf16(aw1, bt, acc[1][dt], 0, 0, 0);
    }
    if (jt < 7) {
      float ss = pfa.x*pfa.x + pfa.y*pfa.y + pfa.z*pfa.z + pfa.w*pfa.w
               + pfb.x*pfb.x + pfb.y*pfb.y + pfb.z*pfb.z + pfb.w*pfb.w;
      u32x4 v;
      v.x = (u32)f2bf(pfa.x) | ((u32)f2bf(pfa.y) << 16);
      v.y = (u32)f2bf(pfa.z) | ((u32)f2bf(pfa.w) << 16);
      v.z = (u32)f2bf(pfb.x) | ((u32)f2bf(pfb.y) << 16);
      v.w = (u32)f2bf(pfb.z) | ((u32)f2bf(pfb.w) << 16);
      stage_tile(v, ss, Kbuf[cur ^ 1], Tbuf[cur ^ 1], INVt[cur ^ 1], wv, q, m16);
    }
    __syncthreads();
  }

  // ---- wave epilogue: h_last += (h_self * m*last) pooled ----
  #pragma unroll
  for (int rt = 0; rt < 2; ++rt) {
    const int i0 = wv * 32 + rt * 16;
    float rws[4];
    #pragma unroll
    for (int r = 0; r < 4; ++r) {
      float s = wpart[rt][r];
      s += __shfl_xor(s, 1); s += __shfl_xor(s, 2);
      s += __shfl_xor(s, 4); s += __shfl_xor(s, 8);
      rws[r] = 1.f / s;
    }
    #pragma unroll
    for (int dt = 0; dt < 8; ++dt) {
      float v = 0.f;
      #pragma unroll
      for (int r = 0; r < 4; ++r)
        v += acc[rt][dt][r] * rws[r] * LM[i0 + q * 4 + r];
      v += __shfl_xor(v, 16);
      v += __shfl_xor(v, 32);
      if (q == 0) atomicAdd(&HLacc[dt * 16 + m16], v);
    }
  }

  // ---- residual pooled term: sum_i LM[i]*h1[i][d] (f32, coalesced) ----
  {
    const int dd = t & 127, ig = t >> 7;     // 4 groups x 64 rows
    float p = 0.f;
    #pragma unroll 8
    for (int n = 0; n < 64; ++n) {
      const int i = ig * 64 + n;
      p += LM[i] * h1b[i * 128 + dd];
    }
    ((float*)WST)[ig * 128 + dd] = p;
  }
  __syncthreads();
  if (t < 128) {
    const float* PSf = (const float*)WST;
    HLacc[t] += PSf[t] + PSf[128 + t] + PSf[256 + t] + PSf[384 + t];
  }
  __syncthreads();

  // ---- cross cosine attention over h2 (f32) ----
  if (t < 64) {
    float s = HLacc[t] * HLacc[t] + HLacc[t + 64] * HLacc[t + 64];
    s += __shfl_xor(s, 1); s += __shfl_xor(s, 2); s += __shfl_xor(s, 4);
    s += __shfl_xor(s, 8); s += __shfl_xor(s, 16); s += __shfl_xor(s, 32);
    if (t == 0) SC[0] = rsqrtf(s + 0.01f);
  }
  if (t < 256) MK[t] = (seq1[b * 256 + t] != 0) ? 1.f : 0.f;
  __syncthreads();
  const float* h2b = h2g + (size_t)b * 32768;
  {
    const int k = t >> 1, half = t & 1;
    const float4* r = (const float4*)(h2b + k * 128 + half * 64);
    const float* hl = &HLacc[half * 64];
    float dot = 0.f, ss = 0.f;
    #pragma unroll
    for (int ii = 0; ii < 16; ++ii) {
      const float4 vv = r[ii];
      dot += vv.x * hl[ii*4] + vv.y * hl[ii*4+1] + vv.z * hl[ii*4+2] + vv.w * hl[ii*4+3];
      ss  += vv.x*vv.x + vv.y*vv.y + vv.z*vv.z + vv.w*vv.w;
    }
    dot += __shfl_xor(dot, 1);
    ss  += __shfl_xor(ss, 1);
    if (half == 0) LM[k] = __expf(dot * rsqrtf(ss + 0.01f) * SC[0]) * MK[k];
  }
  __syncthreads();
  if (t < 64) {
    float s = LM[t] + LM[t + 64] + LM[t + 128] + LM[t + 192];
    s += __shfl_xor(s, 1); s += __shfl_xor(s, 2); s += __shfl_xor(s, 4);
    s += __shfl_xor(s, 8); s += __shfl_xor(s, 16); s += __shfl_xor(s, 32);
    if (t == 0) SC[1] = s;
  }
  __syncthreads();
  {
    const int dd = t & 127, kg = t >> 7;     // 4 groups x 64 rows
    float p = 0.f;
    #pragma unroll 8
    for (int n = 0; n < 64; ++n) {
      const int k = kg * 64 + n;
      p += LM[k] * h2b[k * 128 + dd];
    }
    ((float*)WST)[kg * 128 + dd] = p;
  }
  __syncthreads();
  if (t < 128) {
    const float* PSf = (const float*)WST;
    HH[t] = (PSf[t] + PSf[128 + t] + PSf[256 + t] + PSf[384 + t]) / SC[1];
  }
  __syncthreads();
  if (t < 128) {
    float o = 0.f;
    #pragma unroll 8
    for (int d = 0; d < 128; ++d)
      o += HH[d] * wg[d * 128 + t];
    outg[(size_t)b * 128 + t] = fmaxf(o, 0.f);
  }
}

extern "C" void kernel_launch(void* const* d_in, const int* in_sizes, int n_in,
                              void* d_out, int out_size, void* d_ws, size_t ws_size,
                              hipStream_t stream) {
  (void)in_sizes; (void)n_in; (void)d_ws; (void)ws_size; (void)out_size;
  const int*   seq     = (const int*)d_in[0];
  const int*   lastseq = (const int*)d_in[1];
  const int*   seq1    = (const int*)d_in[2];
  const float* h1      = (const float*)d_in[3];
  const float* h2      = (const float*)d_in[4];
  const float* w       = (const float*)d_in[5];
  float* out           = (float*)d_out;
  itd_fused<<<dim3(512), dim3(512), 0, stream>>>(seq, lastseq, seq1, h1, h2, w, out);
}